// Round 2
// baseline (135.430 us; speedup 1.0000x reference)
//
#include <hip/hip_runtime.h>
#include <math.h>

// Perfusion row-reduce: ct[n] = K * param[n,0] * (sum-trapz over t of log(cp[n,t]/T10[n]))
// Restructured: ln(cp/T10) = ln2*(log2(cp) - log2(T10));
// trapz(a) = sum(a) - 0.5*(a[0] + a[T-1]); T10 term factors out as 4095*log2(T10).
// Memory floor: read 64 MB of cp (raw_s never touched) ~= 10.2 us at 6.3 TB/s.

constexpr int   T_PTS = 4096;
constexpr float LN2   = 0.69314718055994530942f;

__global__ __launch_bounds__(256) void perfusion_row_reduce(
    const float* __restrict__ param,   // [N,3]
    const float* __restrict__ T10,     // [N,1]
    const float* __restrict__ cp,      // [N,T]
    float* __restrict__ out)           // [N]
{
    const int row = blockIdx.x;
    const int tid = threadIdx.x;

    const float4* cpv = (const float4*)(cp + (size_t)row * T_PTS);

    // 4 independent dwordx4 loads issued back-to-back (full MLP), 16 elems/thread
    float4 v0 = cpv[tid];
    float4 v1 = cpv[256 + tid];
    float4 v2 = cpv[512 + tid];
    float4 v3 = cpv[768 + tid];

    float s = __log2f(v0.x) + __log2f(v0.y) + __log2f(v0.z) + __log2f(v0.w)
            + __log2f(v1.x) + __log2f(v1.y) + __log2f(v1.z) + __log2f(v1.w)
            + __log2f(v2.x) + __log2f(v2.y) + __log2f(v2.z) + __log2f(v2.w)
            + __log2f(v3.x) + __log2f(v3.y) + __log2f(v3.z) + __log2f(v3.w);

    // Trapezoid endpoint correction folded into the lanes already holding
    // element 0 (tid 0, v0.x) and element T-1 (tid 255, v3.w): net weight 0.5.
    if (tid == 0)   s -= 0.5f * __log2f(v0.x);
    if (tid == 255) s -= 0.5f * __log2f(v3.w);

    // wave64 butterfly reduce
#pragma unroll
    for (int off = 32; off > 0; off >>= 1)
        s += __shfl_down(s, off, 64);

    __shared__ float ws[4];
    if ((tid & 63) == 0) ws[tid >> 6] = s;
    __syncthreads();

    if (tid == 0) {
        float S = ws[0] + ws[1] + ws[2] + ws[3];
        // W = trapz weights applied to log2(cp) minus (T-1)*log2(T10)
        float W = S - 4095.0f * __log2f(T10[row]);
        float integral = (-LN2 / 32.0f) * W;   // (-1/TE) * ln(...), step/2 pairs fold to weight-1 interior
        float cbv = param[row * 3] * 5.0f;
        float ct = cbv / 100.0f * (1.04f / 1.4f) * ((1.0f - 0.45f) / (1.0f - 0.25f)) * integral;
        out[row] = ct;
    }
}

extern "C" void kernel_launch(void* const* d_in, const int* in_sizes, int n_in,
                              void* d_out, int out_size, void* d_ws, size_t ws_size,
                              hipStream_t stream) {
    const float* param = (const float*)d_in[0];  // [N,3]
    const float* T10   = (const float*)d_in[1];  // [N,1]
    const float* cp    = (const float*)d_in[2];  // [N,T]
    // d_in[3] = raw_s -- unused by the reference; never read (saves 64 MB of HBM traffic)
    float* out = (float*)d_out;                  // [N] float32

    const int N = in_sizes[1];                   // T10 has N elements
    perfusion_row_reduce<<<N, 256, 0, stream>>>(param, T10, cp, out);
}